// Round 5
// baseline (223.812 us; speedup 1.0000x reference)
//
#include <hip/hip_runtime.h>

#define T_FULL 4096
#define D 128
#define K 1024
#define NVEC 65536           // 16*4096
#define BDT 8388608          // 16*128*4096
#define BT 64                // tokens per block (2 waves x 32)
#define NBLK (NVEC / BT)     // 1024 blocks
#define KT 32                // codes per staged tile
#define NIT (K / KT)         // 32 iterations
#define PLANE_B (K * D * 2)  // 262144 bytes per f16 plane
#define TILE_B (2 * KT * D * 2)   // 16384 bytes per staged tile (2 planes)

typedef _Float16 f16x8 __attribute__((ext_vector_type(8)));
typedef float f32x4 __attribute__((ext_vector_type(4)));

#define MFMA(a, b, c) __builtin_amdgcn_mfma_f32_16x16x32_f16((a), (b), (c), 0, 0, 0)

#define GLOAD_LDS(g, l)                                                        \
  __builtin_amdgcn_global_load_lds(                                            \
      (const __attribute__((address_space(1))) unsigned int*)(g),              \
      (__attribute__((address_space(3))) unsigned int*)(l), 16, 0, 0)

// ---------------- prep: zero ws + ee norms + (2e) 2-way fp16 split planes ----------------
__global__ __launch_bounds__(128) void prep_kernel(const float* __restrict__ cb,
    float* __restrict__ ee, _Float16* __restrict__ E1, _Float16* __restrict__ E2,
    unsigned int* __restrict__ counts, unsigned int* __restrict__ done,
    float* __restrict__ loss_acc) {
  int k = blockIdx.x, d = threadIdx.x;
  if (d == 0) {
    counts[k] = 0u;
    if (k == 0) { *done = 0u; *loss_acc = 0.f; }
  }
  float e = cb[k * D + d];
  float v = e * e;
#pragma unroll
  for (int o = 32; o > 0; o >>= 1) v += __shfl_down(v, o, 64);
  __shared__ float tmp[2];
  if ((d & 63) == 0) tmp[d >> 6] = v;
  __syncthreads();
  if (d == 0) ee[k] = tmp[0] + tmp[1];

  float s = 2.0f * e;                       // fold the -2*dot scale (exact)
  _Float16 h1 = (_Float16)s;                // RTN: |s-h1| <= 2^-11 |s|
  _Float16 h2 = (_Float16)(s - (float)h1);  // residual <= 2^-22 |s|
  E1[k * D + d] = h1;
  E2[k * D + d] = h2;
}

// ---------------- main: A-in-regs (fp16 2-split), B dbuf LDS, 4-term MFMA ----------------
__global__ __launch_bounds__(128, 2) void vq_main(
    const float* __restrict__ inp, const float* __restrict__ cb,
    const float* __restrict__ ee, const _Float16* __restrict__ Eplanes,
    unsigned int* __restrict__ counts, unsigned int* __restrict__ done,
    float* __restrict__ loss_acc, float* __restrict__ out) {
  __shared__ __align__(16) _Float16 Bs[2 * 2 * KT * D];   // 32 KB, XOR-swizzled
  __shared__ float ee_sh[K];                              // 4 KB
  __shared__ int   midx[BT];
  __shared__ float lred[2];
  __shared__ int   lastf;

  float* out_q   = out + 1;
  float* out_idx = out + 2 + BDT;

  const int tid  = threadIdx.x;
  const int lane = tid & 63;
  const int w    = tid >> 6;        // wave 0/1: owns tokens w*32..w*32+31
  const int c    = lane & 15;       // MFMA col (code) / token within 16
  const int q    = lane >> 4;       // quad
  const int b    = blockIdx.x >> 6;
  const int t0   = (blockIdx.x & 63) * BT;

  // --- staging offsets: 1024 16B-slots/tile, 8 per thread ---
  // lds slot: [plane p][code][dg'] ; global group dg = dg' ^ (code&15)
  unsigned soff[8], slds[8];
#pragma unroll
  for (int i = 0; i < 8; ++i) {
    int flat = tid + i * 128;              // 0..1023
    int p    = flat >> 9;                  // plane 0/1
    int s    = flat & 511;
    int code = s >> 4;
    int dgp  = s & 15;
    int dg   = dgp ^ (code & 15);
    soff[i] = (unsigned)(p * PLANE_B + code * 256 + dg * 16);
    slds[i] = (unsigned)(flat * 16);       // uniform-base + lane*16 per instr
  }
  const char* Eb = (const char*)Eplanes;

  // --- issue stage of buffer 0 (kt = 0) ---
#pragma unroll
  for (int i = 0; i < 8; ++i)
    GLOAD_LDS(Eb + soff[i], (char*)Bs + slds[i]);

  // --- X -> registers, exact 2-way fp16 split (A-fragment layout) ---
  f16x8 A1[2][4], A2[2][4];
  {
    const float* xin = inp + (size_t)b * D * T_FULL + t0 + w * 32 + c;
#pragma unroll
    for (int n = 0; n < 2; ++n)
#pragma unroll
      for (int dc = 0; dc < 4; ++dc) {
        f16x8 a1, a2;
#pragma unroll
        for (int j = 0; j < 8; ++j) {
          int d = dc * 32 + q * 8 + j;
          float x = xin[(size_t)d * T_FULL + n * 16];
          _Float16 h1 = (_Float16)x;
          _Float16 h2 = (_Float16)(x - (float)h1);
          a1[j] = h1; a2[j] = h2;
        }
        A1[n][dc] = a1; A2[n][dc] = a2;
      }
  }
  // --- ee -> LDS ---
#pragma unroll
  for (int i = tid; i < K; i += 128) ee_sh[i] = ee[i];
  __syncthreads();

  float bv[2][4];
  int   bi[2][4];
#pragma unroll
  for (int n = 0; n < 2; ++n)
#pragma unroll
    for (int r = 0; r < 4; ++r) { bv[n][r] = 3.4e38f; bi[n][r] = 0; }

  for (int it = 0; it < NIT; ++it) {
    const int kt = it * KT;
    const int bb = it & 1;

    // prefetch next tile into buffer bb^1 (wraps harmlessly on last iter)
    {
      const int ktn = (kt + KT) & (K - 1);
      const unsigned lbo = (unsigned)((bb ^ 1) * TILE_B);
#pragma unroll
      for (int i = 0; i < 8; ++i)
        GLOAD_LDS(Eb + (size_t)ktn * 256 + soff[i], (char*)Bs + lbo + slds[i]);
    }

    // compute on buffer bb
    f32x4 acc[2][2];
#pragma unroll
    for (int n = 0; n < 2; ++n)
#pragma unroll
      for (int kf = 0; kf < 2; ++kf) acc[n][kf] = (f32x4){0.f, 0.f, 0.f, 0.f};

    const char* Bp = (const char*)Bs + bb * TILE_B;
#pragma unroll
    for (int dc = 0; dc < 4; ++dc) {
      const int sw = ((dc * 4 + q) ^ c) * 16;       // de-swizzle
      f16x8 B1[2], B2[2];
#pragma unroll
      for (int kf = 0; kf < 2; ++kf) {
        const int ro = (kf * 16 + c) * 256 + sw;
        B1[kf] = *(const f16x8*)(Bp + ro);
        B2[kf] = *(const f16x8*)(Bp + 8192 + ro);
      }
#pragma unroll
      for (int n = 0; n < 2; ++n)
#pragma unroll
        for (int kf = 0; kf < 2; ++kf) {
          f32x4 a = acc[n][kf];
          a = MFMA(A1[n][dc], B1[kf], a);   // keep ALL 4 terms: error ~2^-22
          a = MFMA(A1[n][dc], B2[kf], a);
          a = MFMA(A2[n][dc], B1[kf], a);
          a = MFMA(A2[n][dc], B2[kf], a);
          acc[n][kf] = a;
        }
    }

    // argmin update: dist = ee - 2*x.e ; codes ascending -> strict < = first occurrence
#pragma unroll
    for (int kf = 0; kf < 2; ++kf) {
      const int code = kt + kf * 16 + c;
      const float eev = ee_sh[code];
#pragma unroll
      for (int n = 0; n < 2; ++n)
#pragma unroll
        for (int r = 0; r < 4; ++r) {
          float dist = eev - acc[n][kf][r];
          if (dist < bv[n][r]) { bv[n][r] = dist; bi[n][r] = code; }
        }
    }
    __syncthreads();
  }

  // --- cross-lane argmin over the 16 code-cols (tie -> smaller idx) ---
#pragma unroll
  for (int m = 1; m <= 8; m <<= 1)
#pragma unroll
    for (int n = 0; n < 2; ++n)
#pragma unroll
      for (int r = 0; r < 4; ++r) {
        float ov = __shfl_xor(bv[n][r], m, 64);
        int   oi = __shfl_xor(bi[n][r], m, 64);
        if (ov < bv[n][r] || (ov == bv[n][r] && oi < bi[n][r])) {
          bv[n][r] = ov; bi[n][r] = oi;
        }
      }
  if (c == 0) {
#pragma unroll
    for (int n = 0; n < 2; ++n)
#pragma unroll
      for (int r = 0; r < 4; ++r)
        midx[w * 32 + n * 16 + q * 4 + r] = bi[n][r];
  }
  __syncthreads();

  if (tid < BT) {
    int ki = midx[tid];
    out_idx[(size_t)b * T_FULL + t0 + tid] = (float)ki;
    atomicAdd(&counts[ki], 1u);
  }

  // --- register epilogue: q gathered from cb, x reconstructed from A-regs ---
  float lsum = 0.f;
#pragma unroll
  for (int n = 0; n < 2; ++n) {
    const int tn = w * 32 + n * 16 + c;             // this lane's token
    const int kq = midx[tn];
    const float* crow = cb + (size_t)kq * D;
    float* qbase = out_q + (size_t)b * D * T_FULL + t0 + tn;
#pragma unroll
    for (int dc = 0; dc < 4; ++dc) {
      const int d0 = dc * 32 + q * 8;
      float4 qa = *(const float4*)(crow + d0);
      float4 qb = *(const float4*)(crow + d0 + 4);
      float qv[8] = {qa.x, qa.y, qa.z, qa.w, qb.x, qb.y, qb.z, qb.w};
#pragma unroll
      for (int j = 0; j < 8; ++j) {
        float x = (float)A1[n][dc][j] + (float)A2[n][dc][j];  // exact to 2^-22
        float df = qv[j] - x;
        lsum = fmaf(df, df, lsum);
        qbase[(size_t)(d0 + j) * T_FULL] = qv[j];
      }
    }
  }
#pragma unroll
  for (int o = 32; o > 0; o >>= 1) lsum += __shfl_down(lsum, o, 64);
  if (lane == 0) lred[w] = lsum;
  __syncthreads();
  if (tid == 0) {
    atomicAdd(loss_acc, lred[0] + lred[1]);
    __threadfence();                                   // publish before ticket
    unsigned ticket = atomicAdd(done, 1u);
    lastf = (ticket == NBLK - 1) ? 1 : 0;
  }
  __syncthreads();

  // --- last block: finalize loss + perplexity ---
  if (lastf) {
    __threadfence();
    float ent = 0.f;
#pragma unroll
    for (int i = tid; i < K; i += 128) {
      float cnt = (float)atomicAdd(&counts[i], 0u);    // coherent read
      float p = cnt * (1.0f / (float)NVEC);
      ent = fmaf(p, logf(p + 1e-10f), ent);
    }
#pragma unroll
    for (int o = 32; o > 0; o >>= 1) ent += __shfl_down(ent, o, 64);
    if (lane == 0) lred[w] = ent;
    __syncthreads();
    if (tid == 0) {
      float e = lred[0] + lred[1];
      float l = atomicAdd(loss_acc, 0.f);
      out[0]       = 0.25f * (l / (float)BDT);
      out[1 + BDT] = expf(-e);
    }
  }
}

extern "C" void kernel_launch(void* const* d_in, const int* in_sizes, int n_in,
                              void* d_out, int out_size, void* d_ws, size_t ws_size,
                              hipStream_t stream) {
  const float* inp = (const float*)d_in[0];   // [16,128,4096] fp32
  const float* cb  = (const float*)d_in[1];   // [1024,128] fp32
  float* out = (float*)d_out;                 // [loss | q(BDT) | perp | idx(B*T)]

  char* ws = (char*)d_ws;
  unsigned int* counts  = (unsigned int*)ws;                // 4 KB
  unsigned int* done    = (unsigned int*)(ws + 4096);
  float*        lossacc = (float*)(ws + 4160);
  float*        ee      = (float*)(ws + 8192);              // 4 KB
  _Float16*     E1      = (_Float16*)(ws + 12288);          // 256 KB
  _Float16*     E2      = (_Float16*)(ws + 12288 + PLANE_B);// 256 KB

  prep_kernel<<<K, 128, 0, stream>>>(cb, ee, E1, E2, counts, done, lossacc);
  vq_main<<<NBLK, 128, 0, stream>>>(inp, cb, ee, E1, counts, done, lossacc, out);
}

// Round 6
// 201.705 us; speedup vs baseline: 1.1096x; 1.1096x over previous
//
#include <hip/hip_runtime.h>

#define T_FULL 4096
#define D 128
#define K 1024
#define NVEC 65536           // 16*4096
#define BDT 8388608          // 16*128*4096
#define BT 128               // tokens per block (4 waves x 32)
#define NBLK (NVEC / BT)     // 512 blocks
#define KT 64                // codes per staged tile
#define NIT (K / KT)         // 16 iterations
#define PLANE_B (K * D * 2)  // 262144 bytes per f16 plane
#define TILE_B (2 * KT * D * 2)   // 32768 bytes per staged tile (2 planes)

typedef _Float16 f16x8 __attribute__((ext_vector_type(8)));
typedef float f32x4 __attribute__((ext_vector_type(4)));

#define MFMA(a, b, c) __builtin_amdgcn_mfma_f32_16x16x32_f16((a), (b), (c), 0, 0, 0)

#define GLOAD_LDS(g, l)                                                        \
  __builtin_amdgcn_global_load_lds(                                            \
      (const __attribute__((address_space(1))) unsigned int*)(g),              \
      (__attribute__((address_space(3))) unsigned int*)(l), 16, 0, 0)

// ---------------- prep: zero ws + ee norms + (2e) 2-way fp16 split planes ----------------
__global__ __launch_bounds__(128) void prep_kernel(const float* __restrict__ cb,
    float* __restrict__ ee, _Float16* __restrict__ E1, _Float16* __restrict__ E2,
    unsigned int* __restrict__ counts, unsigned int* __restrict__ done,
    float* __restrict__ loss_acc) {
  int k = blockIdx.x, d = threadIdx.x;
  if (d == 0) {
    counts[k] = 0u;
    if (k == 0) { *done = 0u; *loss_acc = 0.f; }
  }
  float e = cb[k * D + d];
  float v = e * e;
#pragma unroll
  for (int o = 32; o > 0; o >>= 1) v += __shfl_down(v, o, 64);
  __shared__ float tmp[2];
  if ((d & 63) == 0) tmp[d >> 6] = v;
  __syncthreads();
  if (d == 0) ee[k] = tmp[0] + tmp[1];

  float s = 2.0f * e;                       // fold the -2*dot scale (exact)
  _Float16 h1 = (_Float16)s;                // RTN: |s-h1| <= 2^-11 |s|
  _Float16 h2 = (_Float16)(s - (float)h1);  // residual <= 2^-22 |s|
  E1[k * D + d] = h1;
  E2[k * D + d] = h2;
}

// ---------------- main: A-in-regs (fp16 2-split), B dbuf LDS KT=64, 3-term MFMA ----------------
__global__ __launch_bounds__(256, 2) void vq_main(
    const float* __restrict__ inp, const float* __restrict__ cb,
    const float* __restrict__ ee, const _Float16* __restrict__ Eplanes,
    unsigned int* __restrict__ counts, unsigned int* __restrict__ done,
    float* __restrict__ loss_acc, float* __restrict__ out) {
  __shared__ __align__(16) _Float16 Bs[2 * 2 * KT * D];   // 64 KB, XOR-swizzled
  __shared__ float ee_sh[K];                              // 4 KB
  __shared__ int   midx[BT];
  __shared__ float lred[4];
  __shared__ int   lastf;

  float* out_q   = out + 1;
  float* out_idx = out + 2 + BDT;

  const int tid  = threadIdx.x;
  const int lane = tid & 63;
  const int w    = tid >> 6;        // wave 0..3: owns tokens w*32..w*32+31
  const int c    = lane & 15;       // MFMA col (code) / token within 16
  const int q    = lane >> 4;       // quad
  const int b    = blockIdx.x >> 5;
  const int t0   = (blockIdx.x & 31) * BT;

  // --- staging offsets: 2048 16B-slots/tile, 8 per thread ---
  // lds slot: [plane p][code][dg'] ; global group dg = dg' ^ (code&15)
  unsigned soff[8], slds[8];
#pragma unroll
  for (int i = 0; i < 8; ++i) {
    int flat = tid + i * 256;              // 0..2047
    int p    = flat >> 10;                 // plane 0/1 (1024 slots each)
    int s    = flat & 1023;
    int code = s >> 4;                     // 0..63
    int dgp  = s & 15;
    int dg   = dgp ^ (code & 15);
    soff[i] = (unsigned)(p * PLANE_B + code * 256 + dg * 16);
    slds[i] = (unsigned)(flat * 16);
  }
  const char* Eb = (const char*)Eplanes;

  // --- issue stage of buffer 0 (kt = 0) ---
#pragma unroll
  for (int i = 0; i < 8; ++i)
    GLOAD_LDS(Eb + soff[i], (char*)Bs + slds[i]);

  // --- X -> registers, exact 2-way fp16 split (A-fragment layout) ---
  f16x8 A1[2][4], A2[2][4];
  {
    const float* xin = inp + (size_t)b * D * T_FULL + t0 + w * 32 + c;
#pragma unroll
    for (int n = 0; n < 2; ++n)
#pragma unroll
      for (int dc = 0; dc < 4; ++dc) {
        f16x8 a1, a2;
#pragma unroll
        for (int j = 0; j < 8; ++j) {
          int d = dc * 32 + q * 8 + j;
          float x = xin[(size_t)d * T_FULL + n * 16];
          _Float16 h1 = (_Float16)x;
          _Float16 h2 = (_Float16)(x - (float)h1);
          a1[j] = h1; a2[j] = h2;
        }
        A1[n][dc] = a1; A2[n][dc] = a2;
      }
  }
  // --- ee -> LDS ---
#pragma unroll
  for (int i = tid; i < K; i += 256) ee_sh[i] = ee[i];
  __syncthreads();          // also drains initial staging (vmcnt(0) at barrier)

  float bv[2][4];
  int   bi[2][4];
#pragma unroll
  for (int n = 0; n < 2; ++n)
#pragma unroll
    for (int r = 0; r < 4; ++r) { bv[n][r] = 3.4e38f; bi[n][r] = 0; }

  for (int it = 0; it < NIT; ++it) {
    const int kt = it * KT;
    const int bb = it & 1;

    if (it) __syncthreads();   // protects buf reuse + drains prev staging

    // prefetch next tile into buffer bb^1
    if (it != NIT - 1) {
      const int ktn = kt + KT;
      const unsigned lbo = (unsigned)((bb ^ 1) * TILE_B);
#pragma unroll
      for (int i = 0; i < 8; ++i)
        GLOAD_LDS(Eb + (size_t)ktn * 256 + soff[i], (char*)Bs + lbo + slds[i]);
    }

    // compute on buffer bb
    f32x4 acc[2][4];
#pragma unroll
    for (int n = 0; n < 2; ++n)
#pragma unroll
      for (int kf = 0; kf < 4; ++kf) acc[n][kf] = (f32x4){0.f, 0.f, 0.f, 0.f};

    const char* Bp = (const char*)Bs + bb * TILE_B;
#pragma unroll
    for (int dc = 0; dc < 4; ++dc) {
      const int sw = ((dc * 4 + q) ^ c) * 16;       // de-swizzle
      f16x8 B1[4], B2[4];
#pragma unroll
      for (int kf = 0; kf < 4; ++kf) {
        const int ro = (kf * 16 + c) * 256 + sw;
        B1[kf] = *(const f16x8*)(Bp + ro);
        B2[kf] = *(const f16x8*)(Bp + 16384 + ro);
      }
#pragma unroll
      for (int n = 0; n < 2; ++n)
#pragma unroll
        for (int kf = 0; kf < 4; ++kf) {
          f32x4 a = acc[n][kf];
          a = MFMA(A1[n][dc], B1[kf], a);   // 3-term split: x2*e2 ~2^-22, dropped
          a = MFMA(A1[n][dc], B2[kf], a);
          a = MFMA(A2[n][dc], B1[kf], a);
          acc[n][kf] = a;
        }
    }

    // argmin update: dist = ee - 2*x.e ; codes ascending -> strict < = first occurrence
#pragma unroll
    for (int kf = 0; kf < 4; ++kf) {
      const int code = kt + kf * 16 + c;
      const float eev = ee_sh[code];
#pragma unroll
      for (int n = 0; n < 2; ++n)
#pragma unroll
        for (int r = 0; r < 4; ++r) {
          float dist = eev - acc[n][kf][r];
          if (dist < bv[n][r]) { bv[n][r] = dist; bi[n][r] = code; }
        }
    }
  }

  // --- cross-lane argmin over the 16 code-cols (tie -> smaller idx) ---
#pragma unroll
  for (int m = 1; m <= 8; m <<= 1)
#pragma unroll
    for (int n = 0; n < 2; ++n)
#pragma unroll
      for (int r = 0; r < 4; ++r) {
        float ov = __shfl_xor(bv[n][r], m, 64);
        int   oi = __shfl_xor(bi[n][r], m, 64);
        if (ov < bv[n][r] || (ov == bv[n][r] && oi < bi[n][r])) {
          bv[n][r] = ov; bi[n][r] = oi;
        }
      }
  if (c == 0) {
#pragma unroll
    for (int n = 0; n < 2; ++n)
#pragma unroll
      for (int r = 0; r < 4; ++r)
        midx[w * 32 + n * 16 + q * 4 + r] = bi[n][r];
  }
  __syncthreads();

  if (tid < BT) {
    int ki = midx[tid];
    out_idx[(size_t)b * T_FULL + t0 + tid] = (float)ki;
    atomicAdd(&counts[ki], 1u);
  }

  // --- register epilogue: q gathered from cb, x reconstructed from A-regs ---
  float lsum = 0.f;
#pragma unroll
  for (int n = 0; n < 2; ++n) {
    const int tn = w * 32 + n * 16 + c;             // this lane's token
    const int kq = midx[tn];
    const float* crow = cb + (size_t)kq * D;
    float* qbase = out_q + (size_t)b * D * T_FULL + t0 + tn;
#pragma unroll
    for (int dc = 0; dc < 4; ++dc) {
      const int d0 = dc * 32 + q * 8;
      float4 qa = *(const float4*)(crow + d0);
      float4 qb = *(const float4*)(crow + d0 + 4);
      float qv[8] = {qa.x, qa.y, qa.z, qa.w, qb.x, qb.y, qb.z, qb.w};
#pragma unroll
      for (int j = 0; j < 8; ++j) {
        float x = (float)A1[n][dc][j] + (float)A2[n][dc][j];  // exact to 2^-22
        float df = qv[j] - x;
        lsum = fmaf(df, df, lsum);
        qbase[(size_t)(d0 + j) * T_FULL] = qv[j];
      }
    }
  }
#pragma unroll
  for (int o = 32; o > 0; o >>= 1) lsum += __shfl_down(lsum, o, 64);
  if (lane == 0) lred[w] = lsum;
  __syncthreads();
  if (tid == 0) {
    atomicAdd(loss_acc, lred[0] + lred[1] + lred[2] + lred[3]);
    __threadfence();                                   // publish before ticket
    unsigned ticket = atomicAdd(done, 1u);
    lastf = (ticket == NBLK - 1) ? 1 : 0;
  }
  __syncthreads();

  // --- last block: finalize loss + perplexity ---
  if (lastf) {
    __threadfence();
    float ent = 0.f;
#pragma unroll
    for (int i = tid; i < K; i += 256) {
      float cnt = (float)atomicAdd(&counts[i], 0u);    // coherent read
      float p = cnt * (1.0f / (float)NVEC);
      ent = fmaf(p, logf(p + 1e-10f), ent);
    }
#pragma unroll
    for (int o = 32; o > 0; o >>= 1) ent += __shfl_down(ent, o, 64);
    if (lane == 0) lred[w] = ent;
    __syncthreads();
    if (tid == 0) {
      float e = lred[0] + lred[1] + lred[2] + lred[3];
      float l = atomicAdd(loss_acc, 0.f);
      out[0]       = 0.25f * (l / (float)BDT);
      out[1 + BDT] = expf(-e);
    }
  }
}

extern "C" void kernel_launch(void* const* d_in, const int* in_sizes, int n_in,
                              void* d_out, int out_size, void* d_ws, size_t ws_size,
                              hipStream_t stream) {
  const float* inp = (const float*)d_in[0];   // [16,128,4096] fp32
  const float* cb  = (const float*)d_in[1];   // [1024,128] fp32
  float* out = (float*)d_out;                 // [loss | q(BDT) | perp | idx(B*T)]

  char* ws = (char*)d_ws;
  unsigned int* counts  = (unsigned int*)ws;                // 4 KB
  unsigned int* done    = (unsigned int*)(ws + 4096);
  float*        lossacc = (float*)(ws + 4160);
  float*        ee      = (float*)(ws + 8192);              // 4 KB
  _Float16*     E1      = (_Float16*)(ws + 12288);          // 256 KB
  _Float16*     E2      = (_Float16*)(ws + 12288 + PLANE_B);// 256 KB

  prep_kernel<<<K, 128, 0, stream>>>(cb, ee, E1, E2, counts, done, lossacc);
  vq_main<<<NBLK, 256, 0, stream>>>(inp, cb, ee, E1, counts, done, lossacc, out);
}

// Round 7
// 182.760 us; speedup vs baseline: 1.2246x; 1.1037x over previous
//
#include <hip/hip_runtime.h>

#define T_FULL 4096
#define D 128
#define K 1024
#define NVEC 65536           // 16*4096
#define BDT 8388608          // 16*128*4096
#define BT 128               // tokens per block (4 waves x 32)
#define NBLK (NVEC / BT)     // 512 blocks
#define KT 64                // codes per staged tile
#define NIT (K / KT)         // 16 iterations
#define PLANE_B (K * D * 2)  // 262144 bytes per f16 plane
#define TILE_B (2 * KT * D * 2)   // 32768 bytes per staged tile (2 planes)

typedef _Float16 f16x8 __attribute__((ext_vector_type(8)));
typedef float f32x4 __attribute__((ext_vector_type(4)));

#define MFMA(a, b, c) __builtin_amdgcn_mfma_f32_16x16x32_f16((a), (b), (c), 0, 0, 0)

#define GLOAD_LDS(g, l)                                                        \
  __builtin_amdgcn_global_load_lds(                                            \
      (const __attribute__((address_space(1))) unsigned int*)(g),              \
      (__attribute__((address_space(3))) unsigned int*)(l), 16, 0, 0)

// ---------------- prep: zero ws + ee norms + (2e) 2-way fp16 split planes ----------------
__global__ __launch_bounds__(128) void prep_kernel(const float* __restrict__ cb,
    float* __restrict__ ee, _Float16* __restrict__ E1, _Float16* __restrict__ E2,
    unsigned int* __restrict__ counts, unsigned int* __restrict__ done,
    float* __restrict__ loss_acc) {
  int k = blockIdx.x, d = threadIdx.x;
  if (d == 0) {
    counts[k] = 0u;
    if (k == 0) { *done = 0u; *loss_acc = 0.f; }
  }
  float e = cb[k * D + d];
  float v = e * e;
#pragma unroll
  for (int o = 32; o > 0; o >>= 1) v += __shfl_down(v, o, 64);
  __shared__ float tmp[2];
  if ((d & 63) == 0) tmp[d >> 6] = v;
  __syncthreads();
  if (d == 0) ee[k] = tmp[0] + tmp[1];

  float s = 2.0f * e;                       // fold the -2*dot scale (exact)
  _Float16 h1 = (_Float16)s;                // RTN: |s-h1| <= 2^-11 |s|
  _Float16 h2 = (_Float16)(s - (float)h1);  // residual <= 2^-22 |s|
  E1[k * D + d] = h1;
  E2[k * D + d] = h2;
}

// ---------------- main: A-in-regs (fp16 2-split), B dbuf LDS KT=64, 3-term MFMA ----------------
__global__ __launch_bounds__(256, 2) void vq_main(
    const float* __restrict__ inp, const float* __restrict__ cb,
    const float* __restrict__ ee, const _Float16* __restrict__ Eplanes,
    unsigned int* __restrict__ counts, unsigned int* __restrict__ done,
    float* __restrict__ loss_acc, float* __restrict__ out) {
  __shared__ __align__(16) _Float16 Bs[2 * 2 * KT * D];   // 64 KB, XOR-swizzled
  __shared__ float ee_sh[K];                              // 4 KB
  __shared__ int   midx[BT];
  __shared__ float lred[4];
  __shared__ int   lastf;

  float* out_q   = out + 1;
  float* out_idx = out + 2 + BDT;

  const int tid  = threadIdx.x;
  const int lane = tid & 63;
  const int w    = tid >> 6;        // wave 0..3: owns tokens w*32..w*32+31
  const int c    = lane & 15;       // MFMA col (code) / token within 16
  const int q    = lane >> 4;       // quad
  const int b    = blockIdx.x >> 5;
  const int t0   = (blockIdx.x & 31) * BT;

  // --- staging offsets: 2048 16B-slots/tile, 8 per thread ---
  // lds slot: [plane p][code][dg'] ; global group dg = dg' ^ (code&15)
  unsigned soff[8], slds[8];
#pragma unroll
  for (int i = 0; i < 8; ++i) {
    int flat = tid + i * 256;              // 0..2047
    int p    = flat >> 10;                 // plane 0/1 (1024 slots each)
    int s    = flat & 1023;
    int code = s >> 4;                     // 0..63
    int dgp  = s & 15;
    int dg   = dgp ^ (code & 15);
    soff[i] = (unsigned)(p * PLANE_B + code * 256 + dg * 16);
    slds[i] = (unsigned)(flat * 16);
  }
  const char* Eb = (const char*)Eplanes;

  // --- issue stage of buffer 0 (kt = 0) ---
#pragma unroll
  for (int i = 0; i < 8; ++i)
    GLOAD_LDS(Eb + soff[i], (char*)Bs + slds[i]);

  // --- X -> registers, exact 2-way fp16 split (A-fragment layout) ---
  f16x8 A1[2][4], A2[2][4];
  {
    const float* xin = inp + (size_t)b * D * T_FULL + t0 + w * 32 + c;
#pragma unroll
    for (int n = 0; n < 2; ++n)
#pragma unroll
      for (int dc = 0; dc < 4; ++dc) {
        f16x8 a1, a2;
#pragma unroll
        for (int j = 0; j < 8; ++j) {
          int d = dc * 32 + q * 8 + j;
          float x = xin[(size_t)d * T_FULL + n * 16];
          _Float16 h1 = (_Float16)x;
          _Float16 h2 = (_Float16)(x - (float)h1);
          a1[j] = h1; a2[j] = h2;
        }
        A1[n][dc] = a1; A2[n][dc] = a2;
      }
  }
  // --- ee -> LDS ---
#pragma unroll
  for (int i = tid; i < K; i += 256) ee_sh[i] = ee[i];
  __syncthreads();          // also drains initial staging (vmcnt(0) at barrier)

  float bv[2][4];
  int   bi[2][4];
#pragma unroll
  for (int n = 0; n < 2; ++n)
#pragma unroll
    for (int r = 0; r < 4; ++r) { bv[n][r] = 3.4e38f; bi[n][r] = 0; }

  for (int it = 0; it < NIT; ++it) {
    const int kt = it * KT;
    const int bb = it & 1;

    if (it) __syncthreads();   // protects buf reuse + drains prev staging

    // prefetch next tile into buffer bb^1
    if (it != NIT - 1) {
      const int ktn = kt + KT;
      const unsigned lbo = (unsigned)((bb ^ 1) * TILE_B);
#pragma unroll
      for (int i = 0; i < 8; ++i)
        GLOAD_LDS(Eb + (size_t)ktn * 256 + soff[i], (char*)Bs + lbo + slds[i]);
    }

    // compute on buffer bb
    f32x4 acc[2][4];
#pragma unroll
    for (int n = 0; n < 2; ++n)
#pragma unroll
      for (int kf = 0; kf < 4; ++kf) acc[n][kf] = (f32x4){0.f, 0.f, 0.f, 0.f};

    const char* Bp = (const char*)Bs + bb * TILE_B;
#pragma unroll
    for (int dc = 0; dc < 4; ++dc) {
      const int sw = ((dc * 4 + q) ^ c) * 16;       // de-swizzle
      f16x8 B1[4], B2[4];
#pragma unroll
      for (int kf = 0; kf < 4; ++kf) {
        const int ro = (kf * 16 + c) * 256 + sw;
        B1[kf] = *(const f16x8*)(Bp + ro);
        B2[kf] = *(const f16x8*)(Bp + 16384 + ro);
      }
#pragma unroll
      for (int n = 0; n < 2; ++n)
#pragma unroll
        for (int kf = 0; kf < 4; ++kf) {
          f32x4 a = acc[n][kf];
          a = MFMA(A1[n][dc], B1[kf], a);   // 3-term split: x2*e2 ~2^-22, dropped
          a = MFMA(A1[n][dc], B2[kf], a);
          a = MFMA(A2[n][dc], B1[kf], a);
          acc[n][kf] = a;
        }
    }

    // argmin update: dist = ee - 2*x.e ; codes ascending -> strict < = first occurrence
#pragma unroll
    for (int kf = 0; kf < 4; ++kf) {
      const int code = kt + kf * 16 + c;
      const float eev = ee_sh[code];
#pragma unroll
      for (int n = 0; n < 2; ++n)
#pragma unroll
        for (int r = 0; r < 4; ++r) {
          float dist = eev - acc[n][kf][r];
          if (dist < bv[n][r]) { bv[n][r] = dist; bi[n][r] = code; }
        }
    }
  }

  // --- cross-lane argmin over the 16 code-cols (tie -> smaller idx) ---
#pragma unroll
  for (int m = 1; m <= 8; m <<= 1)
#pragma unroll
    for (int n = 0; n < 2; ++n)
#pragma unroll
      for (int r = 0; r < 4; ++r) {
        float ov = __shfl_xor(bv[n][r], m, 64);
        int   oi = __shfl_xor(bi[n][r], m, 64);
        if (ov < bv[n][r] || (ov == bv[n][r] && oi < bi[n][r])) {
          bv[n][r] = ov; bi[n][r] = oi;
        }
      }
  if (c == 0) {
#pragma unroll
    for (int n = 0; n < 2; ++n)
#pragma unroll
      for (int r = 0; r < 4; ++r)
        midx[w * 32 + n * 16 + q * 4 + r] = bi[n][r];
  }
  __syncthreads();

  if (tid < BT) {
    int ki = midx[tid];
    out_idx[(size_t)b * T_FULL + t0 + tid] = (float)ki;
    atomicAdd(&counts[ki], 1u);
  }

  // --- coalesced epilogue (R3 pattern): thread=token, full-line q stores ---
  // wave = 64 consecutive tokens -> 256-B store segments per d; x re-read is L2-hot
  float lsum = 0.f;
  {
    const int t  = tid & 127;
    const int dh = tid >> 7;            // d-half: 0..63 / 64..127
    const int kq = midx[t];
    const float* crow = cb + (size_t)kq * D + dh * 64;
    const float* xrow = inp + ((size_t)b * D + dh * 64) * T_FULL + t0 + t;
    float*       qrow = out_q + ((size_t)b * D + dh * 64) * T_FULL + t0 + t;
#pragma unroll
    for (int dd = 0; dd < 64; dd += 4) {
      float4 qv = *(const float4*)(crow + dd);
      float x0 = xrow[(size_t)(dd + 0) * T_FULL];
      float x1 = xrow[(size_t)(dd + 1) * T_FULL];
      float x2 = xrow[(size_t)(dd + 2) * T_FULL];
      float x3 = xrow[(size_t)(dd + 3) * T_FULL];
      float df;
      df = qv.x - x0; lsum = fmaf(df, df, lsum); qrow[(size_t)(dd + 0) * T_FULL] = qv.x;
      df = qv.y - x1; lsum = fmaf(df, df, lsum); qrow[(size_t)(dd + 1) * T_FULL] = qv.y;
      df = qv.z - x2; lsum = fmaf(df, df, lsum); qrow[(size_t)(dd + 2) * T_FULL] = qv.z;
      df = qv.w - x3; lsum = fmaf(df, df, lsum); qrow[(size_t)(dd + 3) * T_FULL] = qv.w;
    }
  }
#pragma unroll
  for (int o = 32; o > 0; o >>= 1) lsum += __shfl_down(lsum, o, 64);
  if (lane == 0) lred[w] = lsum;
  __syncthreads();
  if (tid == 0) {
    atomicAdd(loss_acc, lred[0] + lred[1] + lred[2] + lred[3]);
    __threadfence();                                   // publish before ticket
    unsigned ticket = atomicAdd(done, 1u);
    lastf = (ticket == NBLK - 1) ? 1 : 0;
  }
  __syncthreads();

  // --- last block: finalize loss + perplexity ---
  if (lastf) {
    __threadfence();
    float ent = 0.f;
#pragma unroll
    for (int i = tid; i < K; i += 256) {
      float cnt = (float)atomicAdd(&counts[i], 0u);    // coherent read
      float p = cnt * (1.0f / (float)NVEC);
      ent = fmaf(p, logf(p + 1e-10f), ent);
    }
#pragma unroll
    for (int o = 32; o > 0; o >>= 1) ent += __shfl_down(ent, o, 64);
    if (lane == 0) lred[w] = ent;
    __syncthreads();
    if (tid == 0) {
      float e = lred[0] + lred[1] + lred[2] + lred[3];
      float l = atomicAdd(loss_acc, 0.f);
      out[0]       = 0.25f * (l / (float)BDT);
      out[1 + BDT] = expf(-e);
    }
  }
}

extern "C" void kernel_launch(void* const* d_in, const int* in_sizes, int n_in,
                              void* d_out, int out_size, void* d_ws, size_t ws_size,
                              hipStream_t stream) {
  const float* inp = (const float*)d_in[0];   // [16,128,4096] fp32
  const float* cb  = (const float*)d_in[1];   // [1024,128] fp32
  float* out = (float*)d_out;                 // [loss | q(BDT) | perp | idx(B*T)]

  char* ws = (char*)d_ws;
  unsigned int* counts  = (unsigned int*)ws;                // 4 KB
  unsigned int* done    = (unsigned int*)(ws + 4096);
  float*        lossacc = (float*)(ws + 4160);
  float*        ee      = (float*)(ws + 8192);              // 4 KB
  _Float16*     E1      = (_Float16*)(ws + 12288);          // 256 KB
  _Float16*     E2      = (_Float16*)(ws + 12288 + PLANE_B);// 256 KB

  prep_kernel<<<K, 128, 0, stream>>>(cb, ee, E1, E2, counts, done, lossacc);
  vq_main<<<NBLK, 256, 0, stream>>>(inp, cb, ee, E1, counts, done, lossacc, out);
}